// Round 6
// baseline (437.266 us; speedup 1.0000x reference)
//
#include <hip/hip_runtime.h>

#define HID 128
#define NODES 2032
#define NPT 127
#define NBLK 512

typedef _Float16 f16x8 __attribute__((ext_vector_type(8)));
typedef _Float16 f16x4 __attribute__((ext_vector_type(4)));
typedef _Float16 f16x2 __attribute__((ext_vector_type(2)));
typedef float f32x4 __attribute__((ext_vector_type(4)));

// post-order index (within one 127-node tree) of the p-th node at a level
// whose subtree size is sst = 2^(L+1)-1
__device__ __forceinline__ int tree_idx(int p, int sst) {
  return (p + 1) * sst + p - __popc(p) - 1;
}

__global__ void leaf_kernel(const float* __restrict__ embed, const int* __restrict__ word_idx,
                            float* __restrict__ Hf, _Float16* __restrict__ Hh) {
  int leaf = blockIdx.x;                  // 0..1023
  int tree = leaf >> 6, p = leaf & 63;
  int g = tree * NPT + 2 * p - __popc(p); // leaf: L=0, sst=1
  int wi = word_idx[g];
  const float2 e = ((const float2*)(embed + (size_t)wi * HID))[threadIdx.x];
  ((float2*)(Hf + (size_t)g * HID))[threadIdx.x] = e;
  f16x2 hv; hv[0] = (_Float16)e.x; hv[1] = (_Float16)e.y;
  ((f16x2*)(Hh + (size_t)g * HID))[threadIdx.x] = hv;
}

__device__ __forceinline__ void grid_barrier(int* ctr, int nb) {
  __syncthreads();
  if (threadIdx.x == 0) {
    __hip_atomic_fetch_add(ctr, 1, __ATOMIC_ACQ_REL, __HIP_MEMORY_SCOPE_AGENT);
    while (__hip_atomic_load(ctr, __ATOMIC_RELAXED, __HIP_MEMORY_SCOPE_AGENT) < nb)
      __builtin_amdgcn_s_sleep(16);
    (void)__hip_atomic_load(ctr, __ATOMIC_ACQUIRE, __HIP_MEMORY_SCOPE_AGENT);
  }
  __syncthreads();
}

// Persistent fused kernel: block = (h = bid>>2, kq = bid&3). Stages V[h][64kq..][*]
// as fp16 into LDS (XOR-swizzled) once; loops all 6 levels with per-h flag sync
// (partials) + grid barrier (H visibility). xVx via mfma_f32_16x16x32_f16 with
// fp32 step-2 contraction; W-term partial folded into the same per-block partial.
__global__ __launch_bounds__(256, 2) void fused_kernel(
    const float* __restrict__ V, const float* __restrict__ W, const float* __restrict__ bb,
    const int* __restrict__ left, const int* __restrict__ right,
    float* __restrict__ Hf, _Float16* __restrict__ Hh,
    float* __restrict__ pbuf, int* __restrict__ syncb)
{
  __shared__ _Float16 Vlds[64 * 256];   // 32 KB, swizzled rows of 512 B
  __shared__ float Wstrip[64];
  __shared__ float red[4][64];
  __shared__ float xsave[512];

  const int bid = blockIdx.x;
  const int h = bid >> 2, kq = bid & 3;
  const int tid = threadIdx.x;
  const int lane = tid & 63, w = tid >> 6;
  const int lo16 = lane & 15, q = lane >> 4;
  char* vb = (char*)Vlds;

  // ---- stage V chunk: 64 rows x 256 cols fp32 -> fp16 LDS (swizzled)
  const float* Vsrc = V + ((size_t)h * 256 + (size_t)kq * 64) * 256;
#pragma unroll
  for (int it = 0; it < 16; ++it) {
    int idx = it * 256 + tid;            // float4 index in 64x64-f4 chunk
    int row = idx >> 6, c4 = idx & 63;
    float4 v = ((const float4*)Vsrc)[idx];
    f16x4 hv;
    hv[0] = (_Float16)v.x; hv[1] = (_Float16)v.y;
    hv[2] = (_Float16)v.z; hv[3] = (_Float16)v.w;
    int wa = (row * 512 + c4 * 8) ^ ((row & 7) << 4);
    *(f16x4*)(vb + wa) = hv;
  }
  if (tid < 64) Wstrip[tid] = W[(size_t)(kq * 64 + tid) * HID + h];
  const float bh = bb[h];
  __syncthreads();

  int* bctr  = syncb;        // [6] grid-barrier counters
  int* flags = syncb + 8;    // [6][128] per-h flags
  float* myP = pbuf + (size_t)bid * 512;

  for (int lv = 0; lv < 6; ++lv) {
    const int m = 512 >> lv;
    const int lognpt = 5 - lv;
    const int npt_mask = (1 << lognpt) - 1;
    const int sst = (1 << (lv + 2)) - 1;
    const int ntiles = (m + 63) >> 6;

    for (int t = 0; t < ntiles; ++t) {
      const int n0 = t * 64;
      const int rem = (m - n0) >> 4;
      const int ncf = rem > 4 ? 4 : rem;

      int lg[4], rg[4];
#pragma unroll
      for (int cf = 0; cf < 4; ++cf) {
        if (cf < ncf) {
          int n = n0 + cf * 16 + lo16;
          int tr = n >> lognpt, p = n & npt_mask;
          int g = tr * NPT + tree_idx(p, sst);
          lg[cf] = left[g]; rg[cf] = right[g];
        } else { lg[cf] = 0; rg[cf] = 0; }
      }

      f32x4 acc[4];
#pragma unroll
      for (int cf = 0; cf < 4; ++cf) { f32x4 z = {0.f, 0.f, 0.f, 0.f}; acc[cf] = z; }

#pragma unroll
      for (int l0 = 0; l0 < 256; l0 += 32) {
        const int r = w * 16 + lo16;
        const int ra = (r * 512 + l0 * 2 + q * 16) ^ ((r & 7) << 4);
        const f16x8 Af = *(const f16x8*)(vb + ra);
#pragma unroll
        for (int cf = 0; cf < 4; ++cf) {
          if (cf < ncf) {
            const int child = (l0 < 128) ? lg[cf] : rg[cf];
            const f16x8 Bf = *(const f16x8*)(Hh + (size_t)child * HID + (l0 & 127) + q * 8);
            acc[cf] = __builtin_amdgcn_mfma_f32_16x16x32_f16(Af, Bf, acc[cf], 0, 0, 0);
          }
        }
      }

      // step-2 (fp32 c) + W-strip partial; acc row j -> k = kq*64 + w*16 + q*4 + j
      float part[4];
#pragma unroll
      for (int cf = 0; cf < 4; ++cf) {
        part[cf] = 0.f;
        if (cf < ncf) {
          const int child = (kq < 2) ? lg[cf] : rg[cf];
          const int co = (kq * 64 + w * 16 + q * 4) & 127;
          const f32x4 cv = *(const f32x4*)(Hf + (size_t)child * HID + co);
          part[cf] = cv[0] * acc[cf][0] + cv[1] * acc[cf][1]
                   + cv[2] * acc[cf][2] + cv[3] * acc[cf][3];
          const _Float16* cr = Hh + (size_t)child * HID + co;
          float cw = 0.f;
#pragma unroll
          for (int i = 0; i < 4; ++i)
            cw += (float)cr[i] * Wstrip[w * 16 + q * 4 + i];
          part[cf] += cw;
        }
      }
#pragma unroll
      for (int cf = 0; cf < 4; ++cf) {
        part[cf] += __shfl_xor(part[cf], 16);
        part[cf] += __shfl_xor(part[cf], 32);
      }
      if (q == 0) {
#pragma unroll
        for (int cf = 0; cf < 4; ++cf)
          if (cf < ncf) red[w][cf * 16 + lo16] = part[cf];
      }
      __syncthreads();
      if (w == 0 && lane < ncf * 16) {
        float s = red[0][lane] + red[1][lane] + red[2][lane] + red[3][lane];
        if (kq == 0) xsave[n0 + lane] = s;
        else myP[n0 + lane] = s;
      }
      __syncthreads();
    }

    if (kq != 0) {
      if (tid == 0)
        __hip_atomic_fetch_add(&flags[lv * 128 + h], 1, __ATOMIC_RELEASE, __HIP_MEMORY_SCOPE_AGENT);
    } else {
      if (tid == 0) {
        while (__hip_atomic_load(&flags[lv * 128 + h], __ATOMIC_RELAXED, __HIP_MEMORY_SCOPE_AGENT) < 3)
          __builtin_amdgcn_s_sleep(8);
        (void)__hip_atomic_load(&flags[lv * 128 + h], __ATOMIC_ACQUIRE, __HIP_MEMORY_SCOPE_AGENT);
      }
      __syncthreads();
      const float* p1 = pbuf + (size_t)(h * 4 + 1) * 512;
      const float* p2 = pbuf + (size_t)(h * 4 + 2) * 512;
      const float* p3 = pbuf + (size_t)(h * 4 + 3) * 512;
      for (int n = tid; n < m; n += 256) {
        float xv = xsave[n] + p1[n] + p2[n] + p3[n] + bh;
        float tnh = tanhf(xv);
        int tr = n >> lognpt, p = n & npt_mask;
        int g = tr * NPT + tree_idx(p, sst);
        Hf[(size_t)g * HID + h] = tnh;
        Hh[(size_t)g * HID + h] = (_Float16)tnh;
      }
    }
    if (lv < 5) grid_barrier(&bctr[lv], NBLK);
  }
}

__global__ void out_kernel(const float* __restrict__ Hf, const float* __restrict__ Wout,
                           const float* __restrict__ Wb, float* __restrict__ out) {
  int n = blockIdx.x * blockDim.x + threadIdx.x;
  if (n >= NODES) return;
  const float* hrow = Hf + (size_t)n * HID;
  float lg0 = Wb[0], lg1 = Wb[1], lg2 = Wb[2], lg3 = Wb[3], lg4 = Wb[4];
#pragma unroll
  for (int j = 0; j < 32; ++j) {
    float4 hv = ((const float4*)hrow)[j];
    const float* wr = Wout + (size_t)(j * 4) * 5;
    lg0 += hv.x * wr[0] + hv.y * wr[5] + hv.z * wr[10] + hv.w * wr[15];
    lg1 += hv.x * wr[1] + hv.y * wr[6] + hv.z * wr[11] + hv.w * wr[16];
    lg2 += hv.x * wr[2] + hv.y * wr[7] + hv.z * wr[12] + hv.w * wr[17];
    lg3 += hv.x * wr[3] + hv.y * wr[8] + hv.z * wr[13] + hv.w * wr[18];
    lg4 += hv.x * wr[4] + hv.y * wr[9] + hv.z * wr[14] + hv.w * wr[19];
  }
  float mm = fmaxf(fmaxf(fmaxf(lg0, lg1), fmaxf(lg2, lg3)), lg4);
  float ss = expf(lg0 - mm) + expf(lg1 - mm) + expf(lg2 - mm) + expf(lg3 - mm) + expf(lg4 - mm);
  float lse = mm + logf(ss);
  float* o = out + (size_t)n * 5;
  o[0] = lg0 - lse; o[1] = lg1 - lse; o[2] = lg2 - lse; o[3] = lg3 - lse; o[4] = lg4 - lse;
}

extern "C" void kernel_launch(void* const* d_in, const int* in_sizes, int n_in,
                              void* d_out, int out_size, void* d_ws, size_t ws_size,
                              hipStream_t stream) {
  const float* embed = (const float*)d_in[0];
  const float* V     = (const float*)d_in[1];
  const float* W     = (const float*)d_in[2];
  const float* b     = (const float*)d_in[3];
  const float* Wout  = (const float*)d_in[4];
  const float* Woutb = (const float*)d_in[5];
  // d_in[6] = is_leaf (structural, unused)
  const int* word_idx = (const int*)d_in[7];
  const int* left     = (const int*)d_in[8];
  const int* right    = (const int*)d_in[9];
  float* out = (float*)d_out;

  // ws layout (all 16B-aligned): Hf | pbuf | sync | Hh
  char* wsb = (char*)d_ws;
  float* Hf   = (float*)wsb;                                   // 2032*128 f32 = 1040384 B
  float* pbuf = (float*)(wsb + 1040384);                       // 512*512 f32  = 1048576 B
  int*   syncb = (int*)(wsb + 1040384 + 1048576);              // 4096 B
  _Float16* Hh = (_Float16*)(wsb + 1040384 + 1048576 + 4096);  // 2032*128 f16

  hipMemsetAsync(syncb, 0, 4096, stream);
  leaf_kernel<<<1024, 64, 0, stream>>>(embed, word_idx, Hf, Hh);
  fused_kernel<<<NBLK, 256, 0, stream>>>(V, W, b, left, right, Hf, Hh, pbuf, syncb);
  out_kernel<<<(NODES + 255) / 256, 256, 0, stream>>>(Hf, Wout, Woutb, out);
}